// Round 1
// baseline (32106.659 us; speedup 1.0000x reference)
//
#include <hip/hip_runtime.h>
#include <hip/hip_cooperative_groups.h>

namespace cg = cooperative_groups;

#define B_   128
#define T_   512
#define KV_  128
#define EMB_ 256
#define H1_  512
#define L_   256
#define NVOC 30
#define NPRED (B_*L_*NVOC)
#define NTHR 512
#define XSS  642   // padded LDS stride for x-vector (conflict-free float2 reads)

__device__ __forceinline__ float bf2f(unsigned short u) {
  union { unsigned int u; float f; } c; c.u = ((unsigned int)u) << 16; return c.f;
}
__device__ __forceinline__ unsigned short f2bf(float f) {
  union { float f; unsigned int u; } c; c.f = f;
  unsigned int r = (c.u + 0x7fffu + ((c.u >> 16) & 1u)) >> 16;
  return (unsigned short)r;
}
__device__ __forceinline__ float sigm(float x) { return 1.0f / (1.0f + __expf(-x)); }
__device__ __forceinline__ float tanhh(float x) { return 1.0f - 2.0f / (1.0f + __expf(2.0f * x)); }

struct DecParams {
  const int* y; const int* enc_len;
  const float* W_ih1; const float* W_hh1;
  const float* W_ih2; const float* W_hh2;
  const float* b_ih2; const float* b_hh2;
  const float* table; const unsigned int* keyTp; const unsigned int* value_bf;
  float* H1; float* C1; float* H2; float* C2; float* ctx_state;
  float* qstore; float* ctxstore; float* attn_out;
};

// ---------------------------------------------------------------------------
// prep: build emb-gate table, bf16 transposed key, bf16 value, zero states
// ---------------------------------------------------------------------------
__global__ void prep_kernel(const float* __restrict__ key, const float* __restrict__ value,
                            const float* __restrict__ emb_W, const float* __restrict__ W_ih1,
                            const float* __restrict__ b_ih1, const float* __restrict__ b_hh1,
                            float* __restrict__ table, unsigned int* __restrict__ keyTp,
                            unsigned int* __restrict__ valbf, float* __restrict__ zbase) {
  const int NT_TAB = 31 * 2048;
  const int NT_KEY = B_ * 64 * T_;    // uint entries (d-pairs x t)
  const int NT_VAL = B_ * T_ * 64;    // uint entries
  const int NT_ZER = 2*B_*H1_ + B_*H1_ + 2*B_*KV_ + B_*KV_ + B_*KV_;  // 262144
  const int total = NT_TAB + NT_KEY + NT_VAL + NT_ZER;
  for (int i = blockIdx.x * blockDim.x + threadIdx.x; i < total;
       i += gridDim.x * blockDim.x) {
    if (i < NT_TAB) {
      int row = i & 2047, v = i >> 11;
      float acc = b_ih1[row] + b_hh1[row];
      if (v < NVOC) {
        const float* e = emb_W + v * EMB_;
        const float* w = W_ih1 + row * 384;
        #pragma unroll 4
        for (int k = 0; k < EMB_; ++k) acc += e[k] * w[k];
      }
      table[v * 2048 + row] = acc;
    } else if (i < NT_TAB + NT_KEY) {
      int j = i - NT_TAB;
      int tt = j & (T_ - 1); int r = j >> 9;
      int dp = r & 63; int b = r >> 6;
      int src = (b * T_ + tt) * KV_ + 2 * dp;
      unsigned int lo = f2bf(key[src]), hi = f2bf(key[src + 1]);
      keyTp[((b * 64 + dp) * T_) + tt] = lo | (hi << 16);
    } else if (i < NT_TAB + NT_KEY + NT_VAL) {
      int j = i - NT_TAB - NT_KEY;          // j = (b*T+t)*64 + d2
      int d2 = j & 63; int r = j >> 6;      // r = b*T+t
      int src = r * KV_ + 2 * d2;
      unsigned int lo = f2bf(value[src]), hi = f2bf(value[src + 1]);
      valbf[j] = lo | (hi << 16);
    } else {
      zbase[i - NT_TAB - NT_KEY - NT_VAL] = 0.0f;
    }
  }
}

// ---------------------------------------------------------------------------
// main persistent cooperative kernel: 256 blocks x 512 threads
//   block (bg = blk>>5, ds = blk&31): bg -> 16 batch elems, ds -> dim slice
//   phase1: LSTM1 (16 h1-dims/block), phase2: LSTM2 (4 h2-dims/block),
//   phase3: attention (blocks 0..127, one per batch elem)
// ---------------------------------------------------------------------------
__global__ void __launch_bounds__(NTHR) decoder_main(DecParams P) {
  __shared__ unsigned short W1l[640 * 64];   // 80 KB  [k-pair][64 rows][2]
  __shared__ unsigned short W2l[640 * 16];   // 20 KB
  __shared__ float xs[16 * XSS];             // 40.1 KB staged x-vectors / phase3 overlay
  __shared__ float gbuf[1280];               // gate exchange

  // phase-3 overlays on xs (xs is dead between grid syncs)
  float* e_as  = xs;          // [512] exp values
  float* qs    = xs + 512;    // [128] query
  float* redbf = xs + 640;    // [16] reduction scratch
  float* cbuf  = xs + 704;    // [512] ctx partials

  cg::grid_group grid = cg::this_grid();
  const int blk = blockIdx.x, tid = threadIdx.x;
  const int bg = blk >> 5, ds = blk & 31;
  const int b0 = bg << 4;

  // ---- load bf16 weight slices into LDS (once) ----
  for (int idx = tid; idx < 640 * 64; idx += NTHR) {
    int r = idx / 640, k = idx - r * 640;
    int grow = (r & 3) * 512 + ds * 16 + (r >> 2);   // gate g = r&3, dim = ds*16 + r>>2
    float w = (k < 128) ? P.W_ih1[grow * 384 + 256 + k]
                        : P.W_hh1[grow * 512 + (k - 128)];
    W1l[(k >> 1) * 128 + r * 2 + (k & 1)] = f2bf(w);
  }
  for (int idx = tid; idx < 640 * 16; idx += NTHR) {
    int r = idx / 640, k = idx - r * 640;
    int grow = (r & 3) * 128 + ds * 4 + (r >> 2);
    float w = (k < 512) ? P.W_ih2[grow * 512 + k]
                        : P.W_hh2[grow * 128 + (k - 512)];
    W2l[(k >> 1) * 32 + r * 2 + (k & 1)] = f2bf(w);
  }
  __syncthreads();

  for (int t = 0; t < L_; ++t) {
    const int p = t & 1, np = p ^ 1;

    // ================= Phase 1: LSTM1 =================
    for (int i = tid; i < 16 * 640; i += NTHR) {
      int bl = i / 640, k = i - bl * 640;
      float v = (k < 128) ? P.ctx_state[(b0 + bl) * KV_ + k]
                          : P.H1[p * (B_ * H1_) + (b0 + bl) * H1_ + (k - 128)];
      xs[bl * XSS + k] = v;
    }
    __syncthreads();
    {
      const int o8 = tid & 255;
      const int bl = o8 & 15, d = o8 >> 4, gh = tid >> 8;
      const int g0 = gh << 1;
      const int ci = (t == 0) ? NVOC : P.y[(b0 + bl) * L_ + (t - 1)];
      const int dglob = ds * 16 + d;
      float acc0 = P.table[ci * 2048 + g0 * 512 + dglob];
      float acc1 = P.table[ci * 2048 + (g0 + 1) * 512 + dglob];
      const float* xrow = xs + bl * XSS;
      const unsigned short* wbase = W1l + (d * 4 + g0) * 2;
      #pragma unroll 4
      for (int k2 = 0; k2 < 320; ++k2) {
        float2 x = *(const float2*)(xrow + 2 * k2);
        ushort4 w = *(const ushort4*)(wbase + k2 * 128);
        acc0 += x.x * bf2f(w.x) + x.y * bf2f(w.y);
        acc1 += x.x * bf2f(w.z) + x.y * bf2f(w.w);
      }
      gbuf[o8 * 5 + g0]     = acc0;
      gbuf[o8 * 5 + g0 + 1] = acc1;
    }
    __syncthreads();
    if (tid < 256) {
      const int bl = tid & 15, d = tid >> 4;
      float gi = gbuf[tid * 5 + 0], gf = gbuf[tid * 5 + 1];
      float gg = gbuf[tid * 5 + 2], go = gbuf[tid * 5 + 3];
      const int gidx = (b0 + bl) * H1_ + ds * 16 + d;
      float c  = P.C1[gidx];
      float cn = sigm(gf) * c + sigm(gi) * tanhh(gg);
      float hn = sigm(go) * tanhh(cn);
      P.C1[gidx] = cn;
      P.H1[np * (B_ * H1_) + gidx] = hn;
    }
    grid.sync();

    // ================= Phase 2: LSTM2 =================
    for (int i = tid; i < 16 * 640; i += NTHR) {
      int bl = i / 640, k = i - bl * 640;
      float v = (k < 512) ? P.H1[np * (B_ * H1_) + (b0 + bl) * H1_ + k]
                          : P.H2[p * (B_ * KV_) + (b0 + bl) * KV_ + (k - 512)];
      xs[bl * XSS + k] = v;
    }
    __syncthreads();
    {
      const int o = tid & 255, kh = tid >> 8;
      const int bl = o & 15, r = o >> 4;
      const float* xrow = xs + bl * XSS;
      const unsigned short* wbase = W2l + r * 2;
      float acc = 0.0f;
      const int k2b = kh * 160;
      #pragma unroll 4
      for (int k2i = 0; k2i < 160; ++k2i) {
        int k2 = k2b + k2i;
        float2 x = *(const float2*)(xrow + 2 * k2);
        ushort2 w = *(const ushort2*)(wbase + k2 * 32);
        acc += x.x * bf2f(w.x) + x.y * bf2f(w.y);
      }
      gbuf[o * 2 + kh] = acc;
    }
    __syncthreads();
    if (tid < 64) {
      const int bl = tid & 15, dloc = tid >> 4;
      float g4[4];
      #pragma unroll
      for (int g = 0; g < 4; ++g) {
        const int r = dloc * 4 + g;
        const int o = r * 16 + bl;
        const int grow = g * 128 + ds * 4 + dloc;
        g4[g] = gbuf[o * 2] + gbuf[o * 2 + 1] + P.b_ih2[grow] + P.b_hh2[grow];
      }
      const int gidx = (b0 + bl) * KV_ + ds * 4 + dloc;
      float c  = P.C2[gidx];
      float cn = sigm(g4[1]) * c + sigm(g4[0]) * tanhh(g4[2]);
      float hn = sigm(g4[3]) * tanhh(cn);
      P.C2[gidx] = cn;
      P.H2[np * (B_ * KV_) + gidx] = hn;
      P.qstore[(t * B_ + (b0 + bl)) * KV_ + ds * 4 + dloc] = hn;
    }
    grid.sync();

    // ================= Phase 3: attention (blocks 0..127) =================
    if (blk < B_) {
      const int b = blk;
      if (tid < 128) qs[tid] = P.H2[np * (B_ * KV_) + b * KV_ + tid];
      __syncthreads();
      float e;
      {
        float acc = 0.0f;
        const unsigned int* kp = P.keyTp + b * (64 * T_);
        #pragma unroll 8
        for (int dp = 0; dp < 64; ++dp) {
          unsigned int w = kp[dp * T_ + tid];
          acc += bf2f((unsigned short)(w & 0xffffu)) * qs[2 * dp]
               + bf2f((unsigned short)(w >> 16))     * qs[2 * dp + 1];
        }
        const int len = P.enc_len[b];
        const float SCALE = 0.08838834764831845f;   // 1/sqrt(128)
        e = (tid < len) ? acc * SCALE : -8.8388348e7f;  // (-1e9)*scale
      }
      float m = e;
      #pragma unroll
      for (int off = 32; off > 0; off >>= 1) m = fmaxf(m, __shfl_xor(m, off));
      const int wid = tid >> 6, lane = tid & 63;
      if (lane == 0) redbf[wid] = m;
      __syncthreads();
      float M = redbf[0];
      #pragma unroll
      for (int i2 = 1; i2 < 8; ++i2) M = fmaxf(M, redbf[i2]);
      float pe = __expf(e - M);
      float s = pe;
      #pragma unroll
      for (int off = 32; off > 0; off >>= 1) s += __shfl_xor(s, off);
      if (lane == 0) redbf[8 + wid] = s;
      e_as[tid] = pe;
      __syncthreads();
      float S = 0.0f;
      #pragma unroll
      for (int i2 = 0; i2 < 8; ++i2) S += redbf[8 + i2];
      const float invS = 1.0f / S;
      {
        const int dd = tid & 127, tg = tid >> 7;
        const unsigned short* vb = (const unsigned short*)P.value_bf + b * (T_ * KV_);
        float acc = 0.0f;
        const int tb = tg * 128;
        #pragma unroll 4
        for (int ti = 0; ti < 128; ++ti) {
          int tt = tb + ti;
          acc += e_as[tt] * bf2f(vb[tt * KV_ + dd]);
        }
        cbuf[tg * 128 + dd] = acc;
      }
      __syncthreads();
      if (tid < 128) {
        float cv = (cbuf[tid] + cbuf[128 + tid] + cbuf[256 + tid] + cbuf[384 + tid]) * invS;
        P.ctx_state[b * KV_ + tid] = cv;
        P.ctxstore[(t * B_ + b) * KV_ + tid] = cv;
      }
      if (b == 0) P.attn_out[t * T_ + tid] = pe * invS;
    }
    grid.sync();
  }
}

// ---------------------------------------------------------------------------
// tail: predictions[b][t][v] = [q,ctx] @ emb_W.T + out_b   (fully parallel)
// ---------------------------------------------------------------------------
__global__ void pred_tail(const float* __restrict__ qstore, const float* __restrict__ ctxstore,
                          const float* __restrict__ emb_W, const float* __restrict__ out_b,
                          float* __restrict__ preds) {
  int o = blockIdx.x * 256 + threadIdx.x;
  if (o >= NPRED) return;
  int v = o % NVOC;
  int bt = o / NVOC;
  int b = bt >> 8, t = bt & 255;
  const float* q  = qstore   + (t * B_ + b) * KV_;
  const float* cx = ctxstore + (t * B_ + b) * KV_;
  const float* er = emb_W + v * EMB_;
  float acc = out_b[v];
  #pragma unroll 4
  for (int e = 0; e < 128; ++e) acc += q[e] * er[e] + cx[e] * er[128 + e];
  preds[o] = acc;
}

extern "C" void kernel_launch(void* const* d_in, const int* in_sizes, int n_in,
                              void* d_out, int out_size, void* d_ws, size_t ws_size,
                              hipStream_t stream) {
  const float* key    = (const float*)d_in[0];
  const float* value  = (const float*)d_in[1];
  const int*   enclen = (const int*)d_in[2];
  const int*   y      = (const int*)d_in[3];
  const float* emb_W  = (const float*)d_in[4];
  const float* W_ih1  = (const float*)d_in[5];
  const float* W_hh1  = (const float*)d_in[6];
  const float* b_ih1  = (const float*)d_in[7];
  const float* b_hh1  = (const float*)d_in[8];
  const float* W_ih2  = (const float*)d_in[9];
  const float* W_hh2  = (const float*)d_in[10];
  const float* b_ih2  = (const float*)d_in[11];
  const float* b_hh2  = (const float*)d_in[12];
  const float* out_b  = (const float*)d_in[13];

  float* f = (float*)d_ws;
  float* table = f;                        f += 31 * 2048;
  unsigned int* keyTp = (unsigned int*)f;  f += B_ * 64 * T_;
  unsigned int* valbf = (unsigned int*)f;  f += B_ * T_ * 64;
  float* H1   = f; f += 2 * B_ * H1_;      // zero-region starts at H1
  float* C1   = f; f += B_ * H1_;
  float* H2   = f; f += 2 * B_ * KV_;
  float* C2   = f; f += B_ * KV_;
  float* ctxs = f; f += B_ * KV_;
  float* qstore   = f; f += L_ * B_ * KV_;
  float* ctxstore = f; f += L_ * B_ * KV_;

  float* preds    = (float*)d_out;
  float* attn_out = preds + NPRED;

  prep_kernel<<<4096, 256, 0, stream>>>(key, value, emb_W, W_ih1, b_ih1, b_hh1,
                                        table, keyTp, valbf, H1);

  DecParams P{ y, enclen, W_ih1, W_hh1, W_ih2, W_hh2, b_ih2, b_hh2,
               table, keyTp, valbf, H1, C1, H2, C2, ctxs, qstore, ctxstore, attn_out };
  void* kargs[] = { (void*)&P };
  hipLaunchCooperativeKernel((void*)decoder_main, dim3(256), dim3(NTHR), kargs, 0, stream);

  pred_tail<<<(NPRED + 255) / 256, 256, 0, stream>>>(qstore, ctxstore, emb_W, out_b, preds);
}